// Round 11
// baseline (200.632 us; speedup 1.0000x reference)
//
#include <hip/hip_runtime.h>
#include <hip/hip_bf16.h>
#include <stdint.h>

typedef __bf16 v8bf __attribute__((ext_vector_type(8)));
typedef float  v4f  __attribute__((ext_vector_type(4)));
typedef unsigned short u16;

#define NTOK 16384
#define KDIM 1024

__device__ __forceinline__ u16 f2bf(float f) {
  uint32_t b = __builtin_bit_cast(uint32_t, f);
  b += 0x7FFFu + ((b >> 16) & 1u);
  return (u16)(b >> 16);
}

__device__ __forceinline__ void gl_lds16(const u16* g, u16* l) {
  __builtin_amdgcn_global_load_lds(
      (const __attribute__((address_space(1))) uint32_t*)g,
      (__attribute__((address_space(3))) uint32_t*)l,
      16, 0, 0);
}

__device__ __forceinline__ void bar() {
  __builtin_amdgcn_sched_barrier(0);
  __builtin_amdgcn_s_barrier();
  __builtin_amdgcn_sched_barrier(0);
}
#define LGKM0() do { asm volatile("s_waitcnt lgkmcnt(0)" ::: "memory"); \
                     __builtin_amdgcn_sched_barrier(0); } while (0)
#define VMW(n)  do { asm volatile("s_waitcnt vmcnt(" #n ")" ::: "memory"); \
                     __builtin_amdgcn_sched_barrier(0); } while (0)

// T19: sched_group_barrier emission interleave. Masks (LLVM SchedGroupMask):
// MFMA=0x8, DS_READ=0x100.
#define SGB(m, n) __builtin_amdgcn_sched_group_barrier((m), (n), 0)
// R reads paired 1:1 with the first R MFMAs, remaining MFMAs after.
#define ILV(R) do {                                                           \
  _Pragma("unroll") for (int z = 0; z < (R); ++z) { SGB(0x8,1); SGB(0x100,1);}\
  SGB(0x8, 16 - (R));                                                         \
} while (0)

// ---------------- fused fp32 -> bf16 convert for all three tensors -----
__global__ void cvt_all(const float* __restrict__ x, const float* __restrict__ wq,
                        const float* __restrict__ wp, u16* __restrict__ xo,
                        u16* __restrict__ wqo, u16* __restrict__ wpo) {
  size_t id = (size_t)blockIdx.x * 256 + threadIdx.x;
  const float* src; u16* dst;
  if (id < 2097152)      { src = x  + id * 8;              dst = xo  + id * 8; }
  else if (id < 2490368) { src = wq + (id - 2097152) * 8;  dst = wqo + (id - 2097152) * 8; }
  else                   { src = wp + (id - 2490368) * 8;  dst = wpo + (id - 2490368) * 8; }
  float4 a = *(const float4*)(src);
  float4 b = *(const float4*)(src + 4);
  union { u16 u[8]; uint4 v; } pk;
  pk.u[0]=f2bf(a.x); pk.u[1]=f2bf(a.y); pk.u[2]=f2bf(a.z); pk.u[3]=f2bf(a.w);
  pk.u[4]=f2bf(b.x); pk.u[5]=f2bf(b.y); pk.u[6]=f2bf(b.z); pk.u[7]=f2bf(b.w);
  *(uint4*)(dst) = pk.v;
}

// ---------------- C = A * B^T + bias ; 256x256 tile, BK=64 -------------
// v11 = v10 (persistent rounds + supertile XCD map + pipelined boundary)
// + T19 sched_group_barrier interleave of each phase's post-cluster
// ds_reads INTO its 16-MFMA cluster ({MFMA,DS_READ} 1:1 for the first R).
// Wait/WAR ledger unchanged from v9/v10 (reads still drained by the NEXT
// phase's lgkm0; interleave only changes emission order inside a region;
// frag-reg WAR across cluster/reads is handled by regalloc renaming).
template<int NTOT, bool OUT_BF16, int ROUNDS>
__global__ __launch_bounds__(512, 2)
void gemm_bt(const u16* __restrict__ A, const u16* __restrict__ Bw,
             const float* __restrict__ bias, void* __restrict__ out) {
  constexpr int NM = NTOK / 256;         // 64 = 8 XCDs x 8 rows
  const int bid = blockIdx.x;
  const int xcd = bid & 7, loc = bid >> 3;

  extern __shared__ __align__(16) u16 smem[];  // 2 x 32768 elems = 128 KiB

  const int tid = threadIdx.x, lane = tid & 63, w = tid >> 6;
  const int wr = w >> 2, wc = w & 3;

  v4f acc[8][4];
#pragma unroll
  for (int i = 0; i < 8; ++i)
#pragma unroll
    for (int j = 0; j < 4; ++j) acc[i][j] = v4f{0.f, 0.f, 0.f, 0.f};

  // staging geometry (source-side swizzle; LDS dest linear)
  const int srow = tid >> 3;
  const int sc   = (tid & 7) ^ (srow & 7);
  const size_t soff = (size_t)srow * KDIM + (size_t)sc * 8;
  const u16* Ab; const u16* Bb; int bm, bn;
  auto setbase = [&](int r) {
    int q = r * 32 + loc;
    bm = xcd * 8 + (q & 7);
    bn = q >> 3;
    Ab = A  + (size_t)bm * 256 * KDIM;
    Bb = Bw + (size_t)bn * 256 * KDIM;
  };
  auto stageH = [&](int dstoff, const u16* src) {
    gl_lds16(src + soff, smem + dstoff + (size_t)tid * 8);
    gl_lds16(src + soff + (size_t)64 * KDIM, smem + dstoff + (size_t)tid * 8 + 4096);
  };
  auto prolog = [&]() {   // tiles 0 (buf0) then 1 (buf1): 16 loads
    stageH(0,     Ab);
    stageH(8192,  Ab + (size_t)128 * KDIM);
    stageH(16384, Bb);
    stageH(24576, Bb + (size_t)128 * KDIM);
    stageH(32768 + 16384, Bb + 64);
    stageH(32768 + 24576, Bb + (size_t)128 * KDIM + 64);
    stageH(32768 + 0,     Ab + 64);
    stageH(32768 + 8192,  Ab + (size_t)128 * KDIM + 64);
  };

  // frag reads: read-side swizzle folds to per-lane constants
  const int rA  = lane & 15;
  const int ck0 = (((lane >> 4) ^ (lane & 7)) << 3);
  const int ck1 = ((((lane >> 4) + 4) ^ (lane & 7)) << 3);
  const int ha = wr * 8192;
  const int hb = 16384 + (wc >> 1) * 8192 + (wc & 1) * 64 * 64;

  v8bf Af[4][2], B0r[2][2], B1r[2][2];

#define RD_A(BUF, ROFF) do {                                                  \
  _Pragma("unroll") for (int f = 0; f < 4; ++f) {                             \
    Af[f][0] = *(const v8bf*)(smem + (BUF) + ha + ((ROFF)+f*16+rA)*64 + ck0); \
    Af[f][1] = *(const v8bf*)(smem + (BUF) + ha + ((ROFF)+f*16+rA)*64 + ck1);}\
} while (0)
#define RD_B(BUF, REG, ROFF) do {                                             \
  _Pragma("unroll") for (int g = 0; g < 2; ++g) {                             \
    REG[g][0] = *(const v8bf*)(smem + (BUF) + hb + ((ROFF)+g*16+rA)*64 + ck0);\
    REG[g][1] = *(const v8bf*)(smem + (BUF) + hb + ((ROFF)+g*16+rA)*64 + ck1);}\
} while (0)
#define MM16(FI, GI, BF) do {                                                 \
  __builtin_amdgcn_s_setprio(1);                                              \
  _Pragma("unroll") for (int f = 0; f < 4; ++f)                               \
  _Pragma("unroll") for (int g = 0; g < 2; ++g) {                             \
    acc[(FI)+f][(GI)+g] = __builtin_amdgcn_mfma_f32_16x16x32_bf16(            \
        Af[f][0], BF[g][0], acc[(FI)+f][(GI)+g], 0, 0, 0);                    \
    acc[(FI)+f][(GI)+g] = __builtin_amdgcn_mfma_f32_16x16x32_bf16(            \
        Af[f][1], BF[g][1], acc[(FI)+f][(GI)+g], 0, 0, 0);                    \
  }                                                                           \
  __builtin_amdgcn_s_setprio(0);                                              \
} while (0)

#define TILE(T, D, DN, ST, PR) do {                                           \
  /* P0: no reads in region */                                                \
  LGKM0(); MM16(0, 0, B0r); bar();                                            \
  /* P1: region = 16 MFMA + 8 ds_read (RD_A) */                               \
  VMW(0);                                                                     \
  if (ST) stageH((D) + 16384, Bb + (size_t)((T)+2) * 64);                     \
  LGKM0(); MM16(0, 2, B1r);                                                   \
  RD_A((D), 64);                                                              \
  ILV(8);                                                                     \
  bar();                                                                      \
  /* P2: region = 16 MFMA + 4 ds_read (RD_B) */                               \
  if (ST) stageH((D) + 24576, Bb + (size_t)128*KDIM + (size_t)((T)+2) * 64);  \
  LGKM0(); MM16(4, 2, B1r);                                                   \
  if (PR) { RD_B((DN), B1r, 32); ILV(4); }                                    \
  bar();                                                                      \
  /* P3: region = 16 MFMA + 12 ds_read */                                     \
  if (ST) { stageH((D) + 0,    Ab + (size_t)((T)+2) * 64);                    \
            stageH((D) + 8192, Ab + (size_t)128*KDIM + (size_t)((T)+2)*64); } \
  LGKM0(); MM16(4, 0, B0r);                                                   \
  if (PR) { RD_A((DN), 0); RD_B((DN), B0r, 0); ILV(12); }                     \
  bar();                                                                      \
} while (0)

  // initial prologue (round 0): VMW(8) forces tile0's 8, leaves tile1's 8.
  setbase(0);
  prolog();
  VMW(8);
  bar();
  RD_A(0, 0);
  RD_B(0, B0r, 0);
  RD_B(0, B1r, 32);

  for (int r = 0; r < ROUNDS; ++r) {
    for (int j = 0; j < 7; ++j) {
      TILE(2 * j,     0,     32768, 1, 1);
      TILE(2 * j + 1, 32768, 0,     1, 1);
    }
    TILE(14, 0,     32768, 0, 1);
    TILE(15, 32768, 0,     0, 0);

    const int bmw = bm, bnw = bn;
    if (r + 1 < ROUNDS) { setbase(r + 1); prolog(); }   // loads first

    // C-write (stores issue under the prologue loads)
    {
      const int col0 = bnw * 256 + wc * 64 + (lane & 15);
      const int row0 = bmw * 256 + wr * 128 + ((lane >> 4) << 2);
#pragma unroll
      for (int mf = 0; mf < 8; ++mf) {
#pragma unroll
        for (int nf = 0; nf < 4; ++nf) {
          const int gc = col0 + nf * 16;
          const float bv = bias[gc];
#pragma unroll
          for (int j = 0; j < 4; ++j) {
            const size_t idx = (size_t)(row0 + mf * 16 + j) * NTOT + gc;
            const float v = acc[mf][nf][j] + bv;
            if constexpr (OUT_BF16) ((u16*)out)[idx] = f2bf(v);
            else                    ((float*)out)[idx] = v;
          }
        }
      }
    }

    if (r + 1 < ROUNDS) {
#pragma unroll
      for (int i = 0; i < 8; ++i)
#pragma unroll
        for (int j = 0; j < 4; ++j) acc[i][j] = v4f{0.f, 0.f, 0.f, 0.f};
      VMW(0);          // drain prologue loads (stores ack early at L2)
      bar();
      RD_A(0, 0);
      RD_B(0, B0r, 0);
      RD_B(0, B1r, 32);
    }
  }
#undef TILE
#undef MM16
#undef RD_A
#undef RD_B
}

// ---------------- per-token head-mix attention -------------------------
__global__ __launch_bounds__(256)
void attn_mix(const u16* __restrict__ qkv, u16* __restrict__ outp) {
  __shared__ __align__(16) u16 sq[4][3072];
  __shared__ float sp[4][16][16];
  const int tid = threadIdx.x, lane = tid & 63, w = tid >> 6;
  const size_t tok = (size_t)blockIdx.x * 4 + w;
  const u16* src = qkv + tok * 3072;
#pragma unroll
  for (int i = 0; i < 6; ++i) {
    int t = i * 64 + lane;
    int row = t >> 3;
    int c = (t & 7) ^ (row & 7);
    gl_lds16(src + row * 64 + c * 8, &sq[w][t * 8]);
  }
  __syncthreads();

  const int h = lane >> 2, gb = lane & 3;
  v8bf qv[8];
#pragma unroll
  for (int c = 0; c < 8; ++c)
    qv[c] = *(const v8bf*)&sq[w][h * 64 + ((c ^ (h & 7)) * 8)];

  float s[4];
#pragma unroll
  for (int g4 = 0; g4 < 4; ++g4) {
    const int g = gb * 4 + g4;
    float a = 0.f;
#pragma unroll
    for (int c = 0; c < 8; ++c) {
      v8bf kv = *(const v8bf*)&sq[w][1024 + g * 64 + ((c ^ (g & 7)) * 8)];
#pragma unroll
      for (int j = 0; j < 8; ++j) a += (float)qv[c][j] * (float)kv[j];
    }
    s[g4] = a * 0.125f;
  }
  float m = fmaxf(fmaxf(s[0], s[1]), fmaxf(s[2], s[3]));
  m = fmaxf(m, __shfl_xor(m, 1));
  m = fmaxf(m, __shfl_xor(m, 2));
  float p[4], sum = 0.f;
#pragma unroll
  for (int g4 = 0; g4 < 4; ++g4) { p[g4] = __expf(s[g4] - m); sum += p[g4]; }
  sum += __shfl_xor(sum, 1);
  sum += __shfl_xor(sum, 2);
  const float inv = 1.f / sum;
#pragma unroll
  for (int g4 = 0; g4 < 4; ++g4) sp[w][h][gb * 4 + g4] = p[g4] * inv;
  __syncthreads();

  float o[16];
#pragma unroll
  for (int j = 0; j < 16; ++j) o[j] = 0.f;
  const int db = gb;
#pragma unroll
  for (int g = 0; g < 16; ++g) {
    const float a = sp[w][h][g];
    v8bf v0 = *(const v8bf*)&sq[w][2048 + g * 64 + (((db * 2)     ^ (g & 7)) * 8)];
    v8bf v1 = *(const v8bf*)&sq[w][2048 + g * 64 + (((db * 2 + 1) ^ (g & 7)) * 8)];
#pragma unroll
    for (int j = 0; j < 8; ++j) { o[j] += a * (float)v0[j]; o[8 + j] += a * (float)v1[j]; }
  }
  union { u16 u[16]; uint4 v[2]; } ob;
#pragma unroll
  for (int j = 0; j < 16; ++j) ob.u[j] = f2bf(o[j]);
  u16* dst = outp + tok * 1024 + h * 64 + db * 16;
  *(uint4*)dst = ob.v[0];
  *((uint4*)dst + 1) = ob.v[1];
}

extern "C" void kernel_launch(void* const* d_in, const int* in_sizes, int n_in,
                              void* d_out, int out_size, void* d_ws, size_t ws_size,
                              hipStream_t stream) {
  const float* x      = (const float*)d_in[0];
  const float* w_qkv  = (const float*)d_in[1];
  const float* b_qkv  = (const float*)d_in[2];
  const float* w_proj = (const float*)d_in[3];
  const float* b_proj = (const float*)d_in[4];

  char* ws = (char*)d_ws;
  u16* x_bf    = (u16*)(ws);
  u16* wqkv_bf = (u16*)(ws + (size_t)33554432);
  u16* wp_bf   = (u16*)(ws + (size_t)39845888);
  u16* qkv_bf  = (u16*)(ws + (size_t)41943040);
  u16* at_bf   = (u16*)(ws + (size_t)142606336);

  (void)hipFuncSetAttribute((const void*)&gemm_bt<3072, true, 3>,
                            hipFuncAttributeMaxDynamicSharedMemorySize, 131072);
  (void)hipFuncSetAttribute((const void*)&gemm_bt<1024, false, 1>,
                            hipFuncAttributeMaxDynamicSharedMemorySize, 131072);

  cvt_all<<<dim3(10240), dim3(256), 0, stream>>>(x, w_qkv, w_proj,
                                                 x_bf, wqkv_bf, wp_bf);

  gemm_bt<3072, true, 3><<<dim3(256), dim3(512), 131072, stream>>>(x_bf, wqkv_bf, b_qkv, qkv_bf);
  attn_mix<<<dim3(4096), dim3(256), 0, stream>>>(qkv_bf, at_bf);
  gemm_bt<1024, false, 1><<<dim3(256), dim3(512), 131072, stream>>>(at_bf, wp_bf, b_proj, d_out);
}